// Round 7
// baseline (1274.942 us; speedup 1.0000x reference)
//
#include <hip/hip_runtime.h>

// Brute N^2 neighborlist (upper-triangular pairs), N=6000, P=17,997,000.
// Output layout (flat f32): [0,P) i | [P,2P) j | [2P,3P) d | [3P,6P) r_xyz.
//
// R9 counters (4x replay): WRITE_SIZE exactly 4x432MB (no amplification),
// FETCH 323KB (pos only), VALUBusy 27%, Occ 64%, but 4.3 TB/s effective vs
// the fills' 6.2 TB/s -> store DUTY-CYCLE problem (~30% pipe idle).
// R10 (this round): within-run A/B/C to isolate the mechanism, each variant
// 4x-replayed (idempotent — rewrites identical bytes) to stay in top-5:
//   A <0>: NT stores,    block-per-tile grid (17,576 blocks)  [reference]
//   B <1>: plain stores, block-per-tile grid                  [tests NT]
//   C <2>: plain stores, persistent 2048-block grid-stride    [tests churn]
// Identify rows by Kernel_Name template arg + Start_Timestamp (A,B,C order).
// PBC wrap replicates numpy remainder bitwise; _rn intrinsics forbid
// contraction so the d<=0.5 mask cannot flip vs numpy.

constexpr int NPART  = 6000;
constexpr int NPAIRS = 17997000;     // N*(N-1)/2; % 1024 == 200, % 4 == 0
constexpr float CUT  = 0.5f;
constexpr int TPB = 256;
constexpr int PPT = 4;               // pairs per thread
constexpr int PPB = TPB * PPT;       // 1024 pairs per block
constexpr int NTILES = (NPAIRS + PPB - 1) / PPB;   // 17,576
constexpr int REPS = 4;              // diagnostic replay count
constexpr int PERSIST_BLOCKS = 2048; // 256 CU x 8 blocks

typedef float fvec4 __attribute__((ext_vector_type(4)));

__device__ __forceinline__ int row_start(int i) {
    // pairs before row i: S(i) = i*(N-1) - i*(i-1)/2  (fits int32)
    return i * (NPART - 1) - (i * (i - 1)) / 2;
}

// numpy remainder(r+h, b) - h for |r| < b, b > 0, h = b/2 — bitwise-exact.
__device__ __forceinline__ float pbc_wrap(float r, float b, float h) {
    float v = __fadd_rn(r, h);
    if (v >= b)       v = __fsub_rn(v, b);
    else if (v < 0.f) v = __fadd_rn(v, b);
    return __fsub_rn(v, h);
}

template<bool NT>
__device__ __forceinline__ void st4(float* p, fvec4 v) {
    if constexpr (NT) __builtin_nontemporal_store(v, (fvec4*)p);
    else              *(fvec4*)p = v;
}

// VARIANT 0: NT stores. VARIANT 1/2: plain stores. Grid size set at launch
// (block-per-tile for 0/1, persistent grid-stride for 2).
template<int VARIANT>
__global__ __launch_bounds__(TPB) void nbl_kernel(
    const float* __restrict__ pos,     // [N,3]
    const float* __restrict__ boxv,    // [3,3]
    const int*  __restrict__ is_per,
    float* __restrict__ out)
{
    constexpr bool NT = (VARIANT == 0);
    __shared__ float lds_r[PPB * 3];   // 12,288 B, final r layout per tile

    const int t = threadIdx.x;

    #pragma unroll 1
    for (int rep = 0; rep < REPS; ++rep) {
        #pragma unroll 1
        for (int tile = blockIdx.x; tile < NTILES; tile += gridDim.x) {
            const int pbase = tile * PPB;
            const int p     = pbase + t * PPT;
            // nvalid is 1024 or 200 — always % 4 == 0
            const int nvalid = (NPAIRS - pbase < PPB) ? (NPAIRS - pbase) : PPB;
            const bool active = (t * PPT < nvalid);

            // protect lds_r: previous tile/rep copy-out reads must finish
            __syncthreads();

            float oi[4], oj[4], od[4];

            if (active) {
                // invert triangular index (fp32 estimate + int fixup)
                const float A = 2.0f * NPART - 1.0f;   // 11999
                float disc = A * A - 8.0f * (float)p;
                int i = (int)((A - sqrtf(disc)) * 0.5f);
                if (i < 0) i = 0;
                if (i > NPART - 2) i = NPART - 2;
                while (i < NPART - 2 && row_start(i + 1) <= p) ++i;
                while (i > 0 && row_start(i) > p) --i;
                int j = i + 1 + (p - row_start(i));

                const bool per = (*is_per != 0);
                const float bx = boxv[0], by = boxv[4], bz = boxv[8];
                const float hx = __fmul_rn(bx, 0.5f);
                const float hy = __fmul_rn(by, 0.5f);
                const float hz = __fmul_rn(bz, 0.5f);

                float orr[12];

                if (j + PPT - 1 < NPART) {
                    // FAST PATH: rows j..j+3 are 48 contiguous bytes.
                    const float xi = pos[3 * i + 0];
                    const float yi = pos[3 * i + 1];
                    const float zi = pos[3 * i + 2];
                    fvec4 va, vb, vc;
                    __builtin_memcpy(&va, pos + 3 * j + 0, 16);
                    __builtin_memcpy(&vb, pos + 3 * j + 4, 16);
                    __builtin_memcpy(&vc, pos + 3 * j + 8, 16);
                    const float xj[4] = {va.x, va.w, vb.z, vc.y};
                    const float yj[4] = {va.y, vb.x, vb.w, vc.z};
                    const float zj[4] = {va.z, vb.y, vc.x, vc.w};
                    const float fi = (float)i;

                    #pragma unroll
                    for (int k = 0; k < 4; ++k) {
                        float rx = __fsub_rn(xi, xj[k]);
                        float ry = __fsub_rn(yi, yj[k]);
                        float rz = __fsub_rn(zi, zj[k]);
                        if (per) {
                            rx = pbc_wrap(rx, bx, hx);
                            ry = pbc_wrap(ry, by, hy);
                            rz = pbc_wrap(rz, bz, hz);
                        }
                        float s = __fadd_rn(__fadd_rn(__fmul_rn(rx, rx), __fmul_rn(ry, ry)),
                                            __fmul_rn(rz, rz));
                        float d = __fsqrt_rn(s);
                        bool in = (d <= CUT);

                        oi[k] = in ? fi : -1.0f;
                        oj[k] = in ? (float)(j + k) : -1.0f;
                        od[k] = in ? d : 0.0f;
                        orr[3 * k + 0] = in ? rx : 0.0f;
                        orr[3 * k + 1] = in ? ry : 0.0f;
                        orr[3 * k + 2] = in ? rz : 0.0f;
                    }
                } else {
                    // SLOW PATH: row wrap inside the 4-pair group.
                    float xi = pos[3 * i + 0], yi = pos[3 * i + 1], zi = pos[3 * i + 2];
                    #pragma unroll
                    for (int k = 0; k < 4; ++k) {
                        float xj = pos[3 * j + 0], yj = pos[3 * j + 1], zj = pos[3 * j + 2];
                        float rx = __fsub_rn(xi, xj);
                        float ry = __fsub_rn(yi, yj);
                        float rz = __fsub_rn(zi, zj);
                        if (per) {
                            rx = pbc_wrap(rx, bx, hx);
                            ry = pbc_wrap(ry, by, hy);
                            rz = pbc_wrap(rz, bz, hz);
                        }
                        float s = __fadd_rn(__fadd_rn(__fmul_rn(rx, rx), __fmul_rn(ry, ry)),
                                            __fmul_rn(rz, rz));
                        float d = __fsqrt_rn(s);
                        bool in = (d <= CUT);

                        oi[k] = in ? (float)i : -1.0f;
                        oj[k] = in ? (float)j : -1.0f;
                        od[k] = in ? d : 0.0f;
                        orr[3 * k + 0] = in ? rx : 0.0f;
                        orr[3 * k + 1] = in ? ry : 0.0f;
                        orr[3 * k + 2] = in ? rz : 0.0f;

                        ++j;
                        if (j == NPART) { ++i; j = i + 1;
                            xi = pos[3 * i + 0]; yi = pos[3 * i + 1]; zi = pos[3 * i + 2]; }
                    }
                }

                // stage r-triples in LDS in final layout
                fvec4* lv = (fvec4*)(lds_r + 12 * t);
                lv[0] = (fvec4){orr[0], orr[1], orr[2],  orr[3]};
                lv[1] = (fvec4){orr[4], orr[5], orr[6],  orr[7]};
                lv[2] = (fvec4){orr[8], orr[9], orr[10], orr[11]};
            }

            __syncthreads();

            if (active) {
                st4<NT>(out + p,              (fvec4){oi[0], oi[1], oi[2], oi[3]});
                st4<NT>(out + NPAIRS + p,     (fvec4){oj[0], oj[1], oj[2], oj[3]});
                st4<NT>(out + 2 * NPAIRS + p, (fvec4){od[0], od[1], od[2], od[3]});
            }

            // stream r out lane-contiguously
            const int nf4 = (3 * nvalid) / 4;             // 768 or 150
            float* rbase = out + 3 * NPAIRS + 3 * pbase;
            const fvec4* rsrc = (const fvec4*)lds_r;
            #pragma unroll
            for (int s = 0; s < 3; ++s) {
                int q = t + TPB * s;
                if (q < nf4) st4<NT>(rbase + 4 * q, rsrc[q]);
            }
        }
    }
}

extern "C" void kernel_launch(void* const* d_in, const int* in_sizes, int n_in,
                              void* d_out, int out_size, void* d_ws, size_t ws_size,
                              hipStream_t stream) {
    const float* pos    = (const float*)d_in[0];
    const float* boxv   = (const float*)d_in[1];
    const int*   is_per = (const int*)d_in[2];
    float* out = (float*)d_out;

    // A: NT stores, block-per-tile (today's reference, replicated within-run)
    nbl_kernel<0><<<NTILES, TPB, 0, stream>>>(pos, boxv, is_per, out);
    // B: plain stores, block-per-tile (isolates NT)
    nbl_kernel<1><<<NTILES, TPB, 0, stream>>>(pos, boxv, is_per, out);
    // C: plain stores, persistent grid-stride (isolates block churn)
    nbl_kernel<2><<<PERSIST_BLOCKS, TPB, 0, stream>>>(pos, boxv, is_per, out);
}

// Round 8
// 443.998 us; speedup vs baseline: 2.8715x; 2.8715x over previous
//
#include <hip/hip_runtime.h>

// Brute N^2 neighborlist (upper-triangular pairs), N=6000, P=17,997,000.
// Output layout (flat f32): [0,P) i | [P,2P) j | [2P,3P) d | [3P,6P) r_xyz.
//
// R9 (4x replay counters): traffic is exactly ideal (WRITE 4x432MB, FETCH
// 323KB, no amplification) yet only 4.3 TB/s effective -> store duty-cycle.
// R10 (A/B/C within-run): A NT+tiles ~410us/4rep; B plain+tiles and C
// plain+persistent both ~285us/4rep (= write floor, absent from top-5).
// Decomposition: 1275 total - 319 overhead - 410(A) => B+C ~546, and each
// has a 275us floor -> both at ~6 TB/s. THE NT FLAG WAS THE ~30% COST:
// nt bypasses L2 allocation (shallow HBM-side merge), plain stores coalesce
// full dirty lines in L2 and drain at burst rate — the fills' own path.
// R11 (this round): ship it. Single pass, PLAIN stores, persistent
// 2048-block grid-stride (C config). Predicted kernel ~72-78us,
// dur_us ~395-420.
// PBC wrap replicates numpy remainder bitwise (Sterbenz-exact branches);
// _rn intrinsics forbid contraction so the d<=0.5 mask cannot flip vs numpy.

constexpr int NPART  = 6000;
constexpr int NPAIRS = 17997000;     // N*(N-1)/2; % 1024 == 200, % 4 == 0
constexpr float CUT  = 0.5f;
constexpr int TPB = 256;
constexpr int PPT = 4;               // pairs per thread
constexpr int PPB = TPB * PPT;       // 1024 pairs per block
constexpr int NTILES = (NPAIRS + PPB - 1) / PPB;   // 17,576
constexpr int PERSIST_BLOCKS = 2048; // 256 CU x 8 blocks

typedef float fvec4 __attribute__((ext_vector_type(4)));

__device__ __forceinline__ int row_start(int i) {
    // pairs before row i: S(i) = i*(N-1) - i*(i-1)/2  (fits int32)
    return i * (NPART - 1) - (i * (i - 1)) / 2;
}

// numpy remainder(r+h, b) - h for |r| < b, b > 0, h = b/2 — bitwise-exact.
__device__ __forceinline__ float pbc_wrap(float r, float b, float h) {
    float v = __fadd_rn(r, h);
    if (v >= b)       v = __fsub_rn(v, b);
    else if (v < 0.f) v = __fadd_rn(v, b);
    return __fsub_rn(v, h);
}

__global__ __launch_bounds__(TPB) void nbl_kernel(
    const float* __restrict__ pos,     // [N,3]
    const float* __restrict__ boxv,    // [3,3]
    const int*  __restrict__ is_per,
    float* __restrict__ out)
{
    __shared__ float lds_r[PPB * 3];   // 12,288 B, final r layout per tile

    const int t = threadIdx.x;

    #pragma unroll 1
    for (int tile = blockIdx.x; tile < NTILES; tile += gridDim.x) {
        const int pbase = tile * PPB;
        const int p     = pbase + t * PPT;
        // nvalid is 1024 or 200 — always % 4 == 0, so each thread's 4 pairs
        // are entirely valid or entirely invalid.
        const int nvalid = (NPAIRS - pbase < PPB) ? (NPAIRS - pbase) : PPB;
        const bool active = (t * PPT < nvalid);

        // protect lds_r: previous tile's copy-out reads must finish
        __syncthreads();

        float oi[4], oj[4], od[4];

        if (active) {
            // invert triangular index (fp32 estimate + int fixup)
            const float A = 2.0f * NPART - 1.0f;   // 11999
            float disc = A * A - 8.0f * (float)p;
            int i = (int)((A - sqrtf(disc)) * 0.5f);
            if (i < 0) i = 0;
            if (i > NPART - 2) i = NPART - 2;
            while (i < NPART - 2 && row_start(i + 1) <= p) ++i;
            while (i > 0 && row_start(i) > p) --i;
            int j = i + 1 + (p - row_start(i));

            const bool per = (*is_per != 0);
            const float bx = boxv[0], by = boxv[4], bz = boxv[8];
            const float hx = __fmul_rn(bx, 0.5f);
            const float hy = __fmul_rn(by, 0.5f);
            const float hz = __fmul_rn(bz, 0.5f);

            float orr[12];

            if (j + PPT - 1 < NPART) {
                // FAST PATH (99.87%): rows j..j+3 are 48 contiguous bytes.
                // Max read: j=5996 -> byte 72000 == end of pos, in bounds.
                const float xi = pos[3 * i + 0];
                const float yi = pos[3 * i + 1];
                const float zi = pos[3 * i + 2];
                fvec4 va, vb, vc;
                __builtin_memcpy(&va, pos + 3 * j + 0, 16);  // jx jy jz  j1x
                __builtin_memcpy(&vb, pos + 3 * j + 4, 16);  // j1y j1z j2x j2y
                __builtin_memcpy(&vc, pos + 3 * j + 8, 16);  // j2z j3x j3y j3z
                const float xj[4] = {va.x, va.w, vb.z, vc.y};
                const float yj[4] = {va.y, vb.x, vb.w, vc.z};
                const float zj[4] = {va.z, vb.y, vc.x, vc.w};
                const float fi = (float)i;

                #pragma unroll
                for (int k = 0; k < 4; ++k) {
                    float rx = __fsub_rn(xi, xj[k]);
                    float ry = __fsub_rn(yi, yj[k]);
                    float rz = __fsub_rn(zi, zj[k]);
                    if (per) {
                        rx = pbc_wrap(rx, bx, hx);
                        ry = pbc_wrap(ry, by, hy);
                        rz = pbc_wrap(rz, bz, hz);
                    }
                    float s = __fadd_rn(__fadd_rn(__fmul_rn(rx, rx), __fmul_rn(ry, ry)),
                                        __fmul_rn(rz, rz));
                    float d = __fsqrt_rn(s);
                    bool in = (d <= CUT);

                    oi[k] = in ? fi : -1.0f;
                    oj[k] = in ? (float)(j + k) : -1.0f;
                    od[k] = in ? d : 0.0f;
                    orr[3 * k + 0] = in ? rx : 0.0f;
                    orr[3 * k + 1] = in ? ry : 0.0f;
                    orr[3 * k + 2] = in ? rz : 0.0f;
                }
            } else {
                // SLOW PATH: row wrap inside the 4-pair group.
                float xi = pos[3 * i + 0], yi = pos[3 * i + 1], zi = pos[3 * i + 2];
                #pragma unroll
                for (int k = 0; k < 4; ++k) {
                    float xj = pos[3 * j + 0], yj = pos[3 * j + 1], zj = pos[3 * j + 2];
                    float rx = __fsub_rn(xi, xj);
                    float ry = __fsub_rn(yi, yj);
                    float rz = __fsub_rn(zi, zj);
                    if (per) {
                        rx = pbc_wrap(rx, bx, hx);
                        ry = pbc_wrap(ry, by, hy);
                        rz = pbc_wrap(rz, bz, hz);
                    }
                    float s = __fadd_rn(__fadd_rn(__fmul_rn(rx, rx), __fmul_rn(ry, ry)),
                                        __fmul_rn(rz, rz));
                    float d = __fsqrt_rn(s);
                    bool in = (d <= CUT);

                    oi[k] = in ? (float)i : -1.0f;
                    oj[k] = in ? (float)j : -1.0f;
                    od[k] = in ? d : 0.0f;
                    orr[3 * k + 0] = in ? rx : 0.0f;
                    orr[3 * k + 1] = in ? ry : 0.0f;
                    orr[3 * k + 2] = in ? rz : 0.0f;

                    ++j;
                    if (j == NPART) { ++i; j = i + 1;
                        xi = pos[3 * i + 0]; yi = pos[3 * i + 1]; zi = pos[3 * i + 2]; }
                }
            }

            // stage r-triples in LDS in final layout (16B-aligned b128 writes;
            // 8 lanes cover all 32 banks once -> conflict-free serialization)
            fvec4* lv = (fvec4*)(lds_r + 12 * t);
            lv[0] = (fvec4){orr[0], orr[1], orr[2],  orr[3]};
            lv[1] = (fvec4){orr[4], orr[5], orr[6],  orr[7]};
            lv[2] = (fvec4){orr[8], orr[9], orr[10], orr[11]};
        }

        __syncthreads();

        // PLAIN stores (through L2): full-dirty-line coalescing in L2 drains
        // to HBM at burst rate — measured 1.4x faster than nt path (R10).
        if (active) {
            *(fvec4*)(out + p)              = (fvec4){oi[0], oi[1], oi[2], oi[3]};
            *(fvec4*)(out + NPAIRS + p)     = (fvec4){oj[0], oj[1], oj[2], oj[3]};
            *(fvec4*)(out + 2 * NPAIRS + p) = (fvec4){od[0], od[1], od[2], od[3]};
        }

        // stream r out lane-contiguously: block owns [3*pbase, 3*pbase+3*nvalid)
        // 3*pbase % 4 == 0, 3*nvalid % 4 == 0 -> float4 granularity exact.
        const int nf4 = (3 * nvalid) / 4;                 // 768 or 150
        fvec4* rdst = (fvec4*)(out + 3 * NPAIRS + 3 * pbase);
        const fvec4* rsrc = (const fvec4*)lds_r;
        #pragma unroll
        for (int s = 0; s < 3; ++s) {
            int q = t + TPB * s;
            if (q < nf4) rdst[q] = rsrc[q];
        }
    }
}

extern "C" void kernel_launch(void* const* d_in, const int* in_sizes, int n_in,
                              void* d_out, int out_size, void* d_ws, size_t ws_size,
                              hipStream_t stream) {
    const float* pos    = (const float*)d_in[0];
    const float* boxv   = (const float*)d_in[1];
    const int*   is_per = (const int*)d_in[2];
    float* out = (float*)d_out;

    nbl_kernel<<<PERSIST_BLOCKS, TPB, 0, stream>>>(pos, boxv, is_per, out);
}